// Round 4
// baseline (331.455 us; speedup 1.0000x reference)
//
#include <hip/hip_runtime.h>
#include <stdint.h>

// NodeLevelInnerProductDecoder: out[b,v,:,:] = zeropad(Z_b) @ zeropad(Z_b)^T
// B=64 graphs, D=128, MAX_NODES=508, 4 views. fp32 in/out.
//
// R1: timed region = harness re-poison fill (session-variable 163-208us, fixed cost)
//     + our kernel. Store floor: 264MB fp32 @ fill-rate ~5.4-6.4 TB/s -> ~41-49us.
// R2: nontemporal stores -> kernel 0.98 fill-units. REGRESSION (NT streaming path
//     ~1.7 TB/s effective).
// R3: plain stores -> kernel 0.69 fill-units (~134us). NT confirmed as culprit.
// R4 (this): output rows are 2032B, view stride 1032256B — not 128B-aligned, so
//     every 128-col tile's 512B row segments have partial cache lines at both ends,
//     shared with a DIFFERENT block on (under blk%8 round-robin) a DIFFERENT XCD ->
//     HBM-level read-modify-write on ~585K contested lines (~30-60us). Fix: block
//     owns 64 FULL-WIDTH rows (x4 views) computed in four 128-col chunks -> all
//     internal edge lines are same-block, L2-merged. 512 blocks + bijective
//     XCD-chunked swizzle (8 slabs of a graph share an XCD's L2).

typedef __bf16          v8bf __attribute__((ext_vector_type(8)));
typedef unsigned short  v8us __attribute__((ext_vector_type(8)));
typedef float           v4f  __attribute__((ext_vector_type(4)));
typedef unsigned int    v4u  __attribute__((ext_vector_type(4)));

#define NMAX 508
#define DD   128
#define NV   4
#define LDC  132   // fp32 C-tile row stride (+4 pad: 2-way bank alias max, free per m136)

__device__ __forceinline__ unsigned short f32_to_bf16_rne(float f) {
    unsigned int u = __builtin_bit_cast(unsigned int, f);
    u = (u + 0x7fffu + ((u >> 16) & 1u)) >> 16;
    return (unsigned short)u;
}

__device__ __forceinline__ v8bf cvt8(v4f lo, v4f hi) {
    v8us u;
    u[0] = f32_to_bf16_rne(lo.x); u[1] = f32_to_bf16_rne(lo.y);
    u[2] = f32_to_bf16_rne(lo.z); u[3] = f32_to_bf16_rne(lo.w);
    u[4] = f32_to_bf16_rne(hi.x); u[5] = f32_to_bf16_rne(hi.y);
    u[6] = f32_to_bf16_rne(hi.z); u[7] = f32_to_bf16_rne(hi.w);
    return __builtin_bit_cast(v8bf, u);
}

__global__ __launch_bounds__(256, 4)
void adj_gram_kernel(const float* __restrict__ z,
                     const int*   __restrict__ counts,
                     float*       __restrict__ out)
{
    // 64 x 132 fp32 = 33.8 KB LDS for C-repack only.
    __shared__ __align__(16) float sC[64 * LDC];

    // XCD-chunked bijective swizzle (512 blocks, 8 XCDs, 64 consecutive wgids/XCD):
    // XCD x handles graphs [8x, 8x+8) -> per-graph z rows + slab-boundary lines
    // stay in one XCD's L2.
    const int blk  = blockIdx.x;                    // 0..511
    const int wgid = (blk & 7) * 64 + (blk >> 3);
    const int b    = wgid >> 3;                     // graph 0..63
    const int i0   = (wgid & 7) * 64;               // 64-row slab 0..7

    const int tid  = threadIdx.x;
    const int lane = tid & 63;
    const int wave = tid >> 6;         // 0..3 : 32-col slice of the 128-col chunk

    // ---- ragged offsets: wave-parallel prefix sum (B = 64 = wave size) ----
    // counts dtype hedge: int64 little-endian high word of values 256..508 is 0.
    const bool is64 = (counts[1] == 0);
    int cnt = is64 ? counts[2 * lane] : counts[lane];
    int inc = cnt;
    #pragma unroll
    for (int s = 1; s < 64; s <<= 1) {
        int t = __shfl_up(inc, s);
        if (lane >= s) inc += t;
    }
    const int n   = __shfl(cnt, b);
    const int off = __shfl(inc, b) - n;   // exclusive prefix at graph b

    const int nx   = wave * 32;
    const int lr   = lane & 15;          // A: m-row / B: n-col within 16-tile
    const int lk   = (lane >> 4) * 8;    // k sub-offset
    const int crow = (lane >> 4) * 4;    // MFMA C row group
    const int rs   = tid >> 5;           // store: row group 0..7
    const int cs   = tid & 31;           // store: 4-float (16B) segment

    const float* zb    = z + (size_t)off * DD;
    const size_t outb  = (size_t)b * NV * (size_t)(NMAX * NMAX);

    // ---- four 128-col chunks covering the full 508-wide slab ----
    for (int jc = 0; jc < 4; ++jc) {
        const int j0 = jc * 128;

        v4f acc[4][2];
        #pragma unroll
        for (int mt = 0; mt < 4; ++mt)
            #pragma unroll
            for (int nt = 0; nt < 2; ++nt) acc[mt][nt] = (v4f)0.0f;

        // MFMA with fragments direct from global (input 12.5MB, L2-resident after
        // first touch; XCD swizzle keeps each graph's z on one L2).
        if (i0 < n && j0 < n) {          // all-zero chunks skip compute, still write
            #pragma unroll
            for (int ks = 0; ks < 4; ++ks) {
                const int ko = ks * 32 + lk;
                v8bf af[4], bfv[2];
                #pragma unroll
                for (int mt = 0; mt < 4; ++mt) {
                    const int r = i0 + mt * 16 + lr;
                    v4f lo = (v4f)0.0f, hi = (v4f)0.0f;
                    if (r < n) {
                        const float* p = zb + (size_t)r * DD + ko;
                        lo = *(const v4f*)p;
                        hi = *(const v4f*)(p + 4);
                    }
                    af[mt] = cvt8(lo, hi);
                }
                #pragma unroll
                for (int nt = 0; nt < 2; ++nt) {
                    const int r = j0 + nx + nt * 16 + lr;
                    v4f lo = (v4f)0.0f, hi = (v4f)0.0f;
                    if (r < n) {
                        const float* p = zb + (size_t)r * DD + ko;
                        lo = *(const v4f*)p;
                        hi = *(const v4f*)(p + 4);
                    }
                    bfv[nt] = cvt8(lo, hi);
                }
                #pragma unroll
                for (int mt = 0; mt < 4; ++mt)
                    #pragma unroll
                    for (int nt = 0; nt < 2; ++nt)
                        acc[mt][nt] = __builtin_amdgcn_mfma_f32_16x16x32_bf16(
                            af[mt], bfv[nt], acc[mt][nt], 0, 0, 0);
            }
        }

        __syncthreads();   // prior chunk's sC reads complete before overwrite

        // repack C (MFMA C layout: col=lane&15, row=(lane>>4)*4+reg) -> row-major
        #pragma unroll
        for (int mt = 0; mt < 4; ++mt)
            #pragma unroll
            for (int nt = 0; nt < 2; ++nt)
                #pragma unroll
                for (int rr = 0; rr < 4; ++rr)
                    sC[(mt * 16 + crow + rr) * LDC + nx + nt * 16 + lr] =
                        acc[mt][nt][rr];
        __syncthreads();

        // store 64 rows x 128 cols x 4 views: plain 16B stores through L2.
        // All chunk-edge + row-junction partial lines of this slab are written by
        // THIS block within a few us -> merge in (one XCD's) L2.
        const int gc = j0 + cs * 4;
        if (gc < NMAX) {                 // col 508..511 of chunk 3
            #pragma unroll
            for (int it = 0; it < 8; ++it) {
                const int r  = it * 8 + rs;
                const int gr = i0 + r;
                if (gr >= NMAX) continue;    // rows 508..511 of last slab
                const v4u v = *(const v4u*)&sC[r * LDC + cs * 4];
                const size_t rowbase = (size_t)gr * NMAX + gc;  // 16B aligned
                #pragma unroll
                for (int vv = 0; vv < NV; ++vv)
                    *(v4u*)(out + outb + (size_t)vv * (size_t)(NMAX * NMAX) + rowbase) = v;
            }
        }
    }
}

extern "C" void kernel_launch(void* const* d_in, const int* in_sizes, int n_in,
                              void* d_out, int out_size, void* d_ws, size_t ws_size,
                              hipStream_t stream) {
    const float* z      = (const float*)d_in[0];
    const int*   counts = (const int*)d_in[1];
    float*       out    = (float*)d_out;
    // 64 graphs x 8 full-width 64-row slabs = 512 blocks
    adj_gram_kernel<<<dim3(512), dim3(256), 0, stream>>>(z, counts, out);
}

// Round 5
// 321.280 us; speedup vs baseline: 1.0317x; 1.0317x over previous
//
#include <hip/hip_runtime.h>
#include <stdint.h>

// NodeLevelInnerProductDecoder: out[b,v,:,:] = zeropad(Z_b) @ zeropad(Z_b)^T
// B=64 graphs, D=128, MAX_NODES=508, 4 views. fp32 in/out.
//
// R1: timed region = harness re-poison fill (session-variable 163-208us, fixed)
//     + our kernel(s). Store floor: 264MB fp32 @ fill-rate 5.4-6.4 TB/s -> 41-49us.
// R2: nontemporal stores REGRESSED (NT ~1.7 TB/s effective). Reverted.
// R3: direct-global fragments, 4 blk/CU -> kernel ~134us (0.69 fill-units).
// R4: full-width slabs (kill cross-block partial-line RMW) -> NEUTRAL (135us).
//     Three different structures all pin at ~134-135us; effective store BW
//     ~2.2 TB/s vs fill's 5.4 on the same buffer. Unexplained ~75us.
// R5 (this): views are identical -> split: k1 = MFMA kernel storing ONLY view 0
//     (66MB stores), k2 = pure replicate view0 -> views1-3 (66MB read, 198MB
//     write, 1 load + 3 stores per thread, no sync, no compute). k2 doubles as
//     the store-path ablation: if the ~2.2 TB/s ceiling hits k2 too, it's
//     environmental; if k2 runs at fill-rate, the fused structure was the cost.

typedef __bf16          v8bf __attribute__((ext_vector_type(8)));
typedef unsigned short  v8us __attribute__((ext_vector_type(8)));
typedef float           v4f  __attribute__((ext_vector_type(4)));
typedef unsigned int    v4u  __attribute__((ext_vector_type(4)));

#define NMAX 508
#define DD   128
#define NV   4
#define IMG  (NMAX * NMAX)          // 258064 floats per view image
#define IMG4 (IMG / 4)              // 64516 vec4s per view image
#define LDC  132   // fp32 C-tile row stride (+4 pad: 2-way bank alias, free)

__device__ __forceinline__ unsigned short f32_to_bf16_rne(float f) {
    unsigned int u = __builtin_bit_cast(unsigned int, f);
    u = (u + 0x7fffu + ((u >> 16) & 1u)) >> 16;
    return (unsigned short)u;
}

__device__ __forceinline__ v8bf cvt8(v4f lo, v4f hi) {
    v8us u;
    u[0] = f32_to_bf16_rne(lo.x); u[1] = f32_to_bf16_rne(lo.y);
    u[2] = f32_to_bf16_rne(lo.z); u[3] = f32_to_bf16_rne(lo.w);
    u[4] = f32_to_bf16_rne(hi.x); u[5] = f32_to_bf16_rne(hi.y);
    u[6] = f32_to_bf16_rne(hi.z); u[7] = f32_to_bf16_rne(hi.w);
    return __builtin_bit_cast(v8bf, u);
}

// ---- k1: Gram tiles -> view 0 only ---------------------------------------
__global__ __launch_bounds__(256, 4)
void adj_gram_kernel(const float* __restrict__ z,
                     const int*   __restrict__ counts,
                     float*       __restrict__ out)
{
    __shared__ __align__(16) float sC[64 * LDC];   // 33.8 KB -> 4 blocks/CU

    const int blk = blockIdx.x;
    const int b   = blk >> 5;          // graph 0..63
    const int ti  = (blk >> 2) & 7;    // 64-row tile 0..7
    const int tj  = blk & 3;           // 128-col tile 0..3
    const int i0  = ti * 64;
    const int j0  = tj * 128;

    const int tid  = threadIdx.x;
    const int lane = tid & 63;
    const int wave = tid >> 6;         // 0..3 : 32-col slice of the 128-col tile

    // ragged offsets: wave-parallel prefix sum (B = 64 = wave size).
    // counts dtype hedge: int64 LE high word of values 256..508 is 0.
    const bool is64 = (counts[1] == 0);
    int cnt = is64 ? counts[2 * lane] : counts[lane];
    int inc = cnt;
    #pragma unroll
    for (int s = 1; s < 64; s <<= 1) {
        int t = __shfl_up(inc, s);
        if (lane >= s) inc += t;
    }
    const int n   = __shfl(cnt, b);
    const int off = __shfl(inc, b) - n;

    const int nx = wave * 32;
    const int lr = lane & 15;
    const int lk = (lane >> 4) * 8;

    v4f acc[4][2];
    #pragma unroll
    for (int mt = 0; mt < 4; ++mt)
        #pragma unroll
        for (int nt = 0; nt < 2; ++nt) acc[mt][nt] = (v4f)0.0f;

    if (i0 < n && j0 < n) {              // all-zero tiles skip compute, still write
        const float* zb = z + (size_t)off * DD;
        #pragma unroll
        for (int ks = 0; ks < 4; ++ks) {
            const int ko = ks * 32 + lk;
            v8bf af[4], bfv[2];
            #pragma unroll
            for (int mt = 0; mt < 4; ++mt) {
                const int r = i0 + mt * 16 + lr;
                v4f lo = (v4f)0.0f, hi = (v4f)0.0f;
                if (r < n) {
                    const float* p = zb + (size_t)r * DD + ko;
                    lo = *(const v4f*)p;
                    hi = *(const v4f*)(p + 4);
                }
                af[mt] = cvt8(lo, hi);
            }
            #pragma unroll
            for (int nt = 0; nt < 2; ++nt) {
                const int r = j0 + nx + nt * 16 + lr;
                v4f lo = (v4f)0.0f, hi = (v4f)0.0f;
                if (r < n) {
                    const float* p = zb + (size_t)r * DD + ko;
                    lo = *(const v4f*)p;
                    hi = *(const v4f*)(p + 4);
                }
                bfv[nt] = cvt8(lo, hi);
            }
            #pragma unroll
            for (int mt = 0; mt < 4; ++mt)
                #pragma unroll
                for (int nt = 0; nt < 2; ++nt)
                    acc[mt][nt] = __builtin_amdgcn_mfma_f32_16x16x32_bf16(
                        af[mt], bfv[nt], acc[mt][nt], 0, 0, 0);
        }
    }

    // repack C (MFMA C layout: col=lane&15, row=(lane>>4)*4+reg) -> row-major
    const int crow = (lane >> 4) * 4;
    #pragma unroll
    for (int mt = 0; mt < 4; ++mt)
        #pragma unroll
        for (int nt = 0; nt < 2; ++nt)
            #pragma unroll
            for (int rr = 0; rr < 4; ++rr)
                sC[(mt * 16 + crow + rr) * LDC + nx + nt * 16 + lr] = acc[mt][nt][rr];
    __syncthreads();

    // store view 0 only: 16B stores through L2
    const int rs = tid >> 5;
    const int cs = tid & 31;
    const int gc = j0 + cs * 4;
    const size_t outb = (size_t)b * NV * (size_t)IMG;
    #pragma unroll
    for (int it = 0; it < 8; ++it) {
        const int r  = it * 8 + rs;
        const int gr = i0 + r;
        if (gr >= NMAX || gc >= NMAX) continue;
        const v4u v = *(const v4u*)&sC[r * LDC + cs * 4];
        *(v4u*)(out + outb + (size_t)gr * NMAX + gc) = v;
    }
}

// ---- k2: replicate view 0 -> views 1..3 (pure stream: 1 load, 3 stores) ----
__global__ __launch_bounds__(256)
void replicate_views_kernel(float* __restrict__ out)
{
    const int idx = blockIdx.x * 256 + threadIdx.x;   // vec4 index within image
    if (idx >= IMG4) return;
    const int b = blockIdx.y;
    float* base = out + (size_t)b * NV * (size_t)IMG + (size_t)idx * 4;
    const v4u v = *(const v4u*)base;
    *(v4u*)(base + IMG)     = v;
    *(v4u*)(base + 2 * IMG) = v;
    *(v4u*)(base + 3 * IMG) = v;
}

extern "C" void kernel_launch(void* const* d_in, const int* in_sizes, int n_in,
                              void* d_out, int out_size, void* d_ws, size_t ws_size,
                              hipStream_t stream) {
    const float* z      = (const float*)d_in[0];
    const int*   counts = (const int*)d_in[1];
    float*       out    = (float*)d_out;
    // k1: 64 graphs x 32 tiles (8x4 of 64x128 over 508 padded nodes)
    adj_gram_kernel<<<dim3(64 * 32), dim3(256), 0, stream>>>(z, counts, out);
    // k2: (ceil(64516/256)=253) x 64 graphs; stream-ordered after k1
    replicate_views_kernel<<<dim3(253, 64), dim3(256), 0, stream>>>(out);
}